// Round 8
// baseline (181.712 us; speedup 1.0000x reference)
//
#include <hip/hip_runtime.h>
#include <math.h>

typedef float f4 __attribute__((ext_vector_type(4)));

// ---------------------------------------------------------------------------
// Kernel 1: E_k = expm(t_k * (M + M0)) via scaling-and-squaring + 12-term
// Taylor. 3x3 only (homogeneous row/col of the 4x4 never contributes since
// x_pad's last coord is 0 and A's last row is 0). One thread per t.
// ---------------------------------------------------------------------------
__global__ void expm_kernel(const float* __restrict__ t,
                            const float* __restrict__ M,
                            const float* __restrict__ M0,
                            float* __restrict__ E_out,
                            int T) {
    int k = blockIdx.x * blockDim.x + threadIdx.x;
    if (k >= T) return;

    float tk = t[k];
    float B[9];
#pragma unroll
    for (int i = 0; i < 9; ++i) B[i] = tk * (M[i] + M0[i]);

    float norm = 0.f;
#pragma unroll
    for (int i = 0; i < 3; ++i) {
        float rs = fabsf(B[i * 3]) + fabsf(B[i * 3 + 1]) + fabsf(B[i * 3 + 2]);
        norm = fmaxf(norm, rs);
    }
    int s = 0;
    while (norm > 0.25f && s < 40) { norm *= 0.5f; ++s; }
    float scale = exp2f((float)(-s));
#pragma unroll
    for (int i = 0; i < 9; ++i) B[i] *= scale;

    float P[9], E[9];
#pragma unroll
    for (int i = 0; i < 9; ++i) { P[i] = (i % 4 == 0) ? 1.f : 0.f; E[i] = P[i]; }
    for (int n = 1; n <= 12; ++n) {
        float inv = 1.0f / (float)n;
        float Q[9];
#pragma unroll
        for (int i = 0; i < 3; ++i)
#pragma unroll
            for (int j = 0; j < 3; ++j)
                Q[i * 3 + j] = (P[i * 3 + 0] * B[0 * 3 + j] +
                                P[i * 3 + 1] * B[1 * 3 + j] +
                                P[i * 3 + 2] * B[2 * 3 + j]) * inv;
#pragma unroll
        for (int i = 0; i < 9; ++i) { P[i] = Q[i]; E[i] += Q[i]; }
    }
    for (int q = 0; q < s; ++q) {
        float Q[9];
#pragma unroll
        for (int i = 0; i < 3; ++i)
#pragma unroll
            for (int j = 0; j < 3; ++j)
                Q[i * 3 + j] = E[i * 3 + 0] * E[0 * 3 + j] +
                               E[i * 3 + 1] * E[1 * 3 + j] +
                               E[i * 3 + 2] * E[2 * 3 + j];
#pragma unroll
        for (int i = 0; i < 9; ++i) E[i] = Q[i];
    }

#pragma unroll
    for (int i = 0; i < 9; ++i) E_out[k * 9 + i] = E[i];
}

// ---------------------------------------------------------------------------
// Kernel 2: rolling-window + LANE-DENSE stores.
// Each block owns one 512-row x-tile, staged to LDS ONCE (x never re-read
// from global across the 64 t-sweeps -> FETCH ~ 6 MB total). Outer t-loop is
// uniform across the grid, so at any instant the whole GPU writes ONE ~6 MB
// contiguous window sweeping slab-by-slab (round 7 proved this is the 2.3 ->
// 3.9 TB/s lever). New this round: store instructions are lane-dense — lane l
// writes f4 index base+l, so one wave store covers 1 KB contiguous (vs R7's
// 48B-strided lanes = 3 KB span at 1/3 density = 3x the per-instruction line
// touches). Plain stores (L2 merges; R5 proved nt amplifies 1.94x).
// 977 blocks x 4 waves ~= 15 waves/CU for latency hiding.
// ---------------------------------------------------------------------------
#define TPB 256
#define TILE_N 512

__global__ __launch_bounds__(TPB) void apply_kernel(const float* __restrict__ x,
                                                    const float* __restrict__ E_all,
                                                    float* __restrict__ out,
                                                    int N, int T) {
    __shared__ __align__(16) float xs[TILE_N * 3];

    const int tid  = threadIdx.x;
    const int tile = blockIdx.x;

    const long n0   = (long)tile * TILE_N;
    const int  rows = min(TILE_N, (int)(N - n0));
    const int  nflt = rows * 3;
    const int  nvec = nflt >> 2;          // full f4 count
    const int  rem0 = nvec << 2;

    // stage x tile once (dense f4; n0*3 divisible by 4 -> 16B aligned)
    const float* xsrc = x + n0 * 3;
    for (int v = tid; v < nvec; v += TPB)
        reinterpret_cast<f4*>(xs)[v] = reinterpret_cast<const f4*>(xsrc)[v];
    for (int v = rem0 + tid; v < nflt; v += TPB)
        xs[v] = xsrc[v];
    __syncthreads();

    const size_t slab4 = (size_t)(N * 3) >> 2;   // f4 per t-slab (N*3 % 4 == 0)
    const size_t base4 = (size_t)(n0 * 3) >> 2;  // f4 offset of this tile

    for (int t = 0; t < T; ++t) {
        const float* Ep = E_all + t * 9;         // block-uniform -> scalar loads
        float E[9];
#pragma unroll
        for (int i = 0; i < 9; ++i) E[i] = Ep[i];

        f4* dst4 = (f4*)out + (size_t)t * slab4 + base4;
        for (int v = tid; v < nvec; v += TPB) {
            const int e0 = v << 2;
            f4 r;
#pragma unroll
            for (int c = 0; c < 4; ++c) {
                const int e = e0 + c;
                const int n = e / 3;             // magic-mul, small ints
                const int i = e - n * 3;
                r[c] = E[i * 3 + 0] * xs[n * 3 + 0] +
                       E[i * 3 + 1] * xs[n * 3 + 1] +
                       E[i * 3 + 2] * xs[n * 3 + 2];
            }
            dst4[v] = r;                          // lane-dense, plain
        }
        float* dstf = out + (size_t)t * (slab4 << 2) + (base4 << 2);
        for (int v = rem0 + tid; v < nflt; v += TPB) {
            const int n = v / 3;
            const int i = v - n * 3;
            dstf[v] = E[i * 3 + 0] * xs[n * 3 + 0] +
                      E[i * 3 + 1] * xs[n * 3 + 1] +
                      E[i * 3 + 2] * xs[n * 3 + 2];
        }
    }
}

extern "C" void kernel_launch(void* const* d_in, const int* in_sizes, int n_in,
                              void* d_out, int out_size, void* d_ws, size_t ws_size,
                              hipStream_t stream) {
    const float* x  = (const float*)d_in[0];   // (N, 3)
    const float* t  = (const float*)d_in[1];   // (T,)
    const float* M  = (const float*)d_in[2];   // (3, 3)
    const float* M0 = (const float*)d_in[3];   // (3, 3)
    // d_in[4] = b (3,) — never contributes: homogeneous coord of x_pad is 0.

    const int N = in_sizes[0] / 3;
    const int T = in_sizes[1];

    float* E_ws = (float*)d_ws;                 // T*9 floats
    float* out  = (float*)d_out;

    expm_kernel<<<(T + 63) / 64, 64, 0, stream>>>(t, M, M0, E_ws, T);

    const int ntiles = (N + TILE_N - 1) / TILE_N;   // 977
    apply_kernel<<<ntiles, TPB, 0, stream>>>(x, E_ws, out, N, T);
}

// Round 9
// 85.350 us; speedup vs baseline: 2.1290x; 2.1290x over previous
//
#include <hip/hip_runtime.h>
#include <math.h>

typedef float f4 __attribute__((ext_vector_type(4)));

// ---------------------------------------------------------------------------
// Kernel 1: E_k = expm(t_k * (M + M0)) via scaling-and-squaring + 12-term
// Taylor. 3x3 only (homogeneous row/col of the 4x4 never contributes since
// x_pad's last coord is 0 and A's last row is 0). One thread per t.
// ---------------------------------------------------------------------------
__global__ void expm_kernel(const float* __restrict__ t,
                            const float* __restrict__ M,
                            const float* __restrict__ M0,
                            float* __restrict__ E_out,
                            int T) {
    int k = blockIdx.x * blockDim.x + threadIdx.x;
    if (k >= T) return;

    float tk = t[k];
    float B[9];
#pragma unroll
    for (int i = 0; i < 9; ++i) B[i] = tk * (M[i] + M0[i]);

    float norm = 0.f;
#pragma unroll
    for (int i = 0; i < 3; ++i) {
        float rs = fabsf(B[i * 3]) + fabsf(B[i * 3 + 1]) + fabsf(B[i * 3 + 2]);
        norm = fmaxf(norm, rs);
    }
    int s = 0;
    while (norm > 0.25f && s < 40) { norm *= 0.5f; ++s; }
    float scale = exp2f((float)(-s));
#pragma unroll
    for (int i = 0; i < 9; ++i) B[i] *= scale;

    float P[9], E[9];
#pragma unroll
    for (int i = 0; i < 9; ++i) { P[i] = (i % 4 == 0) ? 1.f : 0.f; E[i] = P[i]; }
    for (int n = 1; n <= 12; ++n) {
        float inv = 1.0f / (float)n;
        float Q[9];
#pragma unroll
        for (int i = 0; i < 3; ++i)
#pragma unroll
            for (int j = 0; j < 3; ++j)
                Q[i * 3 + j] = (P[i * 3 + 0] * B[0 * 3 + j] +
                                P[i * 3 + 1] * B[1 * 3 + j] +
                                P[i * 3 + 2] * B[2 * 3 + j]) * inv;
#pragma unroll
        for (int i = 0; i < 9; ++i) { P[i] = Q[i]; E[i] += Q[i]; }
    }
    for (int q = 0; q < s; ++q) {
        float Q[9];
#pragma unroll
        for (int i = 0; i < 3; ++i)
#pragma unroll
            for (int j = 0; j < 3; ++j)
                Q[i * 3 + j] = E[i * 3 + 0] * E[0 * 3 + j] +
                               E[i * 3 + 1] * E[1 * 3 + j] +
                               E[i * 3 + 2] * E[2 * 3 + j];
#pragma unroll
        for (int i = 0; i < 9; ++i) E[i] = Q[i];
    }

#pragma unroll
    for (int i = 0; i < 9; ++i) E_out[k * 9 + i] = E[i];
}

// ---------------------------------------------------------------------------
// Kernel 2: R7's rolling-window structure (512 blocks = exactly 2/CU, outer
// t-loop uniform, thread g owns row-group g forever) + two fixes:
//  (a) x hoisted to REGISTERS once (NG=125000 < 131072 threads) -> x is read
//      from global exactly once; t-loop has zero global reads.
//  (b) LANE-DENSE stores via LDS transpose: compute strided (rows 4g..4g+3),
//      write 3 f4 to LDS (stride-48B: 8 lanes tile all 32 banks ->
//      conflict-free), one barrier, read back dense, store dense -> each wave
//      store instruction covers 1 KB contiguous (was 3 KB span at 1/3
//      density = 3x line-touches/instr). Double-buffered LDS: 1 barrier/t.
// Plain stores (R5: nt bypasses L2 merge, 1.94x amplification).
// ---------------------------------------------------------------------------
#define NBLK 512
#define TPB 256

__global__ __launch_bounds__(TPB) void apply_kernel(const float* __restrict__ x,
                                                    const float* __restrict__ E_all,
                                                    float* __restrict__ out,
                                                    int N, int T) {
    const int tid = threadIdx.x;

    if ((N & 3) == 0) {
        __shared__ __align__(16) f4 obuf[2][TPB * 3];   // 2 x 12 KB

        const int NG  = N >> 2;                    // row-groups (4 rows each)
        const int B   = blockIdx.x * TPB;          // block's first group
        const int gid = B + tid;

        const size_t slab4 = (size_t)NG * 3;       // output f4 per t-slab
        const size_t ob0   = (size_t)3 * B;        // block's output f4 base
        if (ob0 >= slab4) return;                  // fully idle block

        // hoist this thread's x rows into registers (read once, ever)
        const bool active = gid < NG;
        const f4* __restrict__ x4 = (const f4*)x;
        f4 xa = {0,0,0,0}, xb = {0,0,0,0}, xc = {0,0,0,0};
        if (active) {
            xa = x4[3 * gid + 0];
            xb = x4[3 * gid + 1];
            xc = x4[3 * gid + 2];
        }

        // store predicates (t-invariant). Garbage LDS slots from inactive
        // threads land at indices >= slab4-ob0 and are never stored.
        const bool p0 = ob0 + (size_t)tid            < slab4;
        const bool p1 = ob0 + (size_t)(TPB + tid)    < slab4;
        const bool p2 = ob0 + (size_t)(2 * TPB + tid) < slab4;

        for (int t = 0; t < T; ++t) {
            const float* Ep = E_all + t * 9;       // uniform -> scalar loads
            const float E0 = Ep[0], E1 = Ep[1], E2 = Ep[2];
            const float E3 = Ep[3], E4 = Ep[4], E5 = Ep[5];
            const float E6 = Ep[6], E7 = Ep[7], E8 = Ep[8];

            // rows: r0=(xa.xyz) r1=(xa.w,xb.xy) r2=(xb.zw,xc.x) r3=(xc.yzw)
            f4 oa, ob, oc;
            oa.x = E0 * xa.x + E1 * xa.y + E2 * xa.z;
            oa.y = E3 * xa.x + E4 * xa.y + E5 * xa.z;
            oa.z = E6 * xa.x + E7 * xa.y + E8 * xa.z;

            oa.w = E0 * xa.w + E1 * xb.x + E2 * xb.y;
            ob.x = E3 * xa.w + E4 * xb.x + E5 * xb.y;
            ob.y = E6 * xa.w + E7 * xb.x + E8 * xb.y;

            ob.z = E0 * xb.z + E1 * xb.w + E2 * xc.x;
            ob.w = E3 * xb.z + E4 * xb.w + E5 * xc.x;
            oc.x = E6 * xb.z + E7 * xb.w + E8 * xc.x;

            oc.y = E0 * xc.y + E1 * xc.z + E2 * xc.w;
            oc.z = E3 * xc.y + E4 * xc.z + E5 * xc.w;
            oc.w = E6 * xc.y + E7 * xc.z + E8 * xc.w;

            // transpose through LDS (48B-stride writes: conflict-free tiling)
            f4* buf = obuf[t & 1];
            buf[3 * tid + 0] = oa;
            buf[3 * tid + 1] = ob;
            buf[3 * tid + 2] = oc;
            __syncthreads();

            // dense stores: lane l <-> f4 l (1 KB contiguous per wave instr)
            f4* dst4 = (f4*)out + (size_t)t * slab4 + ob0;
            if (p0) dst4[tid]            = buf[tid];
            if (p1) dst4[TPB + tid]      = buf[TPB + tid];
            if (p2) dst4[2 * TPB + tid]  = buf[2 * TPB + tid];
        }
    } else {
        // generic scalar fallback (not hit for N % 4 == 0)
        const int gid      = blockIdx.x * TPB + tid;
        const int nthreads = gridDim.x * TPB;
        const size_t total = (size_t)T * (size_t)N * 3;
        for (size_t e = gid; e < total; e += (size_t)nthreads) {
            const size_t slab = (size_t)N * 3;
            const int    t    = (int)(e / slab);
            const size_t r    = e - (size_t)t * slab;
            const int    n    = (int)(r / 3);
            const int    i    = (int)(r - (size_t)n * 3);
            const float* Ep = E_all + t * 9 + i * 3;
            const float* xr = x + (size_t)n * 3;
            out[e] = Ep[0] * xr[0] + Ep[1] * xr[1] + Ep[2] * xr[2];
        }
    }
}

extern "C" void kernel_launch(void* const* d_in, const int* in_sizes, int n_in,
                              void* d_out, int out_size, void* d_ws, size_t ws_size,
                              hipStream_t stream) {
    const float* x  = (const float*)d_in[0];   // (N, 3)
    const float* t  = (const float*)d_in[1];   // (T,)
    const float* M  = (const float*)d_in[2];   // (3, 3)
    const float* M0 = (const float*)d_in[3];   // (3, 3)
    // d_in[4] = b (3,) — never contributes: homogeneous coord of x_pad is 0.

    const int N = in_sizes[0] / 3;
    const int T = in_sizes[1];

    float* E_ws = (float*)d_ws;                 // T*9 floats
    float* out  = (float*)d_out;

    expm_kernel<<<(T + 63) / 64, 64, 0, stream>>>(t, M, M0, E_ws, T);

    apply_kernel<<<NBLK, TPB, 0, stream>>>(x, E_ws, out, N, T);
}

// Round 10
// 84.251 us; speedup vs baseline: 2.1568x; 1.0130x over previous
//
#include <hip/hip_runtime.h>
#include <math.h>

typedef float f4 __attribute__((ext_vector_type(4)));

// ---------------------------------------------------------------------------
// Kernel 1: E_k = expm(t_k * (M + M0)) via scaling-and-squaring + 12-term
// Taylor. 3x3 only (homogeneous row/col of the 4x4 never contributes since
// x_pad's last coord is 0 and A's last row is 0). One thread per t.
// ---------------------------------------------------------------------------
__global__ void expm_kernel(const float* __restrict__ t,
                            const float* __restrict__ M,
                            const float* __restrict__ M0,
                            float* __restrict__ E_out,
                            int T) {
    int k = blockIdx.x * blockDim.x + threadIdx.x;
    if (k >= T) return;

    float tk = t[k];
    float B[9];
#pragma unroll
    for (int i = 0; i < 9; ++i) B[i] = tk * (M[i] + M0[i]);

    float norm = 0.f;
#pragma unroll
    for (int i = 0; i < 3; ++i) {
        float rs = fabsf(B[i * 3]) + fabsf(B[i * 3 + 1]) + fabsf(B[i * 3 + 2]);
        norm = fmaxf(norm, rs);
    }
    int s = 0;
    while (norm > 0.25f && s < 40) { norm *= 0.5f; ++s; }
    float scale = exp2f((float)(-s));
#pragma unroll
    for (int i = 0; i < 9; ++i) B[i] *= scale;

    float P[9], E[9];
#pragma unroll
    for (int i = 0; i < 9; ++i) { P[i] = (i % 4 == 0) ? 1.f : 0.f; E[i] = P[i]; }
    for (int n = 1; n <= 12; ++n) {
        float inv = 1.0f / (float)n;
        float Q[9];
#pragma unroll
        for (int i = 0; i < 3; ++i)
#pragma unroll
            for (int j = 0; j < 3; ++j)
                Q[i * 3 + j] = (P[i * 3 + 0] * B[0 * 3 + j] +
                                P[i * 3 + 1] * B[1 * 3 + j] +
                                P[i * 3 + 2] * B[2 * 3 + j]) * inv;
#pragma unroll
        for (int i = 0; i < 9; ++i) { P[i] = Q[i]; E[i] += Q[i]; }
    }
    for (int q = 0; q < s; ++q) {
        float Q[9];
#pragma unroll
        for (int i = 0; i < 3; ++i)
#pragma unroll
            for (int j = 0; j < 3; ++j)
                Q[i * 3 + j] = E[i * 3 + 0] * E[0 * 3 + j] +
                               E[i * 3 + 1] * E[1 * 3 + j] +
                               E[i * 3 + 2] * E[2 * 3 + j];
#pragma unroll
        for (int i = 0; i < 9; ++i) E[i] = Q[i];
    }

#pragma unroll
    for (int i = 0; i < 9; ++i) E_out[k * 9 + i] = E[i];
}

// ---------------------------------------------------------------------------
// Kernel 2: OUTPUT-DENSE ownership, zero-sync streamer.
// Wave W owns slab-f4s [W*192, W*192+192); lane l stores f4s W*192 + l,
// +64+l, +128+l -> every store instruction is 64 lanes x contiguous 16B =
// 1 KB dense (R9 proved density is the lever: 104 -> 85). Each owned f4
// spans exactly 2 x-rows; those 6 floats are hoisted to REGISTERS once
// (18 floats/thread), phase p = 4J mod 3 selects the component mapping via
// t-invariant cndmask masks. The t-loop is then pure {9 uniform E loads,
// 54 FMA, 24 select, 3 dense plain stores} — NO LDS, NO barrier, NO global
// reads -> continuous store issue, exactly like fillBufferAligned (7 TB/s
// at ~3.5 waves/CU with nothing but back-to-back stores).
// Outer t uniform across the grid -> single ~6 MB rolling write window
// (R7: 1 window = 3.9 TB/s vs ~1000 fronts = 2.4 TB/s; R8 confirmed).
// Plain stores, not nt (R5: nt bypasses L2 merge -> 1.94x amplification).
// ---------------------------------------------------------------------------
#define NBLK 512
#define TPB 256

__global__ __launch_bounds__(TPB) void apply_kernel(const float* __restrict__ x,
                                                    const float* __restrict__ E_all,
                                                    float* __restrict__ out,
                                                    int N, int T) {
    const int tid = threadIdx.x;

    if (((N * 3) & 3) == 0) {
        const int  lane = tid & 63;
        const long wave = ((long)blockIdx.x * TPB + tid) >> 6;   // 0..2047
        const long NG4  = (long)N * 3 / 4;                       // f4 per slab
        const long base = wave * 192;
        if (base >= NG4) return;                                 // idle wave

        // per-slot setup (t-invariant): owned f4 index, phase, 2 x rows
        long J[3];
        int  p[3];
        bool act[3];
        float a0[3], a1[3], a2[3], b0[3], b1[3], b2[3];
#pragma unroll
        for (int k = 0; k < 3; ++k) {
            J[k]   = base + 64 * k + lane;
            act[k] = J[k] < NG4;
            const long e0 = 4 * J[k];
            const long n0 = e0 / 3;
            p[k] = (int)(e0 - n0 * 3);
            const long xo = act[k] ? n0 * 3 : 0;   // clamp OOB lanes
            a0[k] = x[xo + 0]; a1[k] = x[xo + 1]; a2[k] = x[xo + 2];
            b0[k] = x[xo + 3]; b1[k] = x[xo + 4]; b2[k] = x[xo + 5];
        }

        f4* const out4 = (f4*)out;

        for (int t = 0; t < T; ++t) {
            const float* Ep = E_all + t * 9;       // uniform -> scalar loads
            const float E0 = Ep[0], E1 = Ep[1], E2 = Ep[2];
            const float E3 = Ep[3], E4 = Ep[4], E5 = Ep[5];
            const float E6 = Ep[6], E7 = Ep[7], E8 = Ep[8];
            f4* const dst = out4 + (size_t)t * (size_t)NG4;

#pragma unroll
            for (int k = 0; k < 3; ++k) {
                // dots of E rows with x rows A (n0) and B (n0+1)
                const float dA0 = E0 * a0[k] + E1 * a1[k] + E2 * a2[k];
                const float dA1 = E3 * a0[k] + E4 * a1[k] + E5 * a2[k];
                const float dA2 = E6 * a0[k] + E7 * a1[k] + E8 * a2[k];
                const float dB0 = E0 * b0[k] + E1 * b1[k] + E2 * b2[k];
                const float dB1 = E3 * b0[k] + E4 * b1[k] + E5 * b2[k];
                const float dB2 = E6 * b0[k] + E7 * b1[k] + E8 * b2[k];

                // phase-rotated component mapping (masks are t-invariant)
                const bool q0 = (p[k] == 0), q1 = (p[k] == 1);
                f4 r;
                r.x = q0 ? dA0 : (q1 ? dA1 : dA2);
                r.y = q0 ? dA1 : (q1 ? dA2 : dB0);
                r.z = q0 ? dA2 : (q1 ? dB0 : dB1);
                r.w = q0 ? dB0 : (q1 ? dB1 : dB2);

                if (act[k]) dst[J[k]] = r;          // dense: lane l -> f4 +l
            }
        }
    } else {
        // generic scalar fallback (not hit for N*3 % 4 == 0)
        const int gid      = blockIdx.x * TPB + tid;
        const int nthreads = gridDim.x * TPB;
        const size_t total = (size_t)T * (size_t)N * 3;
        for (size_t e = gid; e < total; e += (size_t)nthreads) {
            const size_t slab = (size_t)N * 3;
            const int    t    = (int)(e / slab);
            const size_t r    = e - (size_t)t * slab;
            const int    n    = (int)(r / 3);
            const int    i    = (int)(r - (size_t)n * 3);
            const float* Ep = E_all + t * 9 + i * 3;
            const float* xr = x + (size_t)n * 3;
            out[e] = Ep[0] * xr[0] + Ep[1] * xr[1] + Ep[2] * xr[2];
        }
    }
}

extern "C" void kernel_launch(void* const* d_in, const int* in_sizes, int n_in,
                              void* d_out, int out_size, void* d_ws, size_t ws_size,
                              hipStream_t stream) {
    const float* x  = (const float*)d_in[0];   // (N, 3)
    const float* t  = (const float*)d_in[1];   // (T,)
    const float* M  = (const float*)d_in[2];   // (3, 3)
    const float* M0 = (const float*)d_in[3];   // (3, 3)
    // d_in[4] = b (3,) — never contributes: homogeneous coord of x_pad is 0.

    const int N = in_sizes[0] / 3;
    const int T = in_sizes[1];

    float* E_ws = (float*)d_ws;                 // T*9 floats
    float* out  = (float*)d_out;

    expm_kernel<<<(T + 63) / 64, 64, 0, stream>>>(t, M, M0, E_ws, T);

    apply_kernel<<<NBLK, TPB, 0, stream>>>(x, E_ws, out, N, T);
}

// Round 11
// 83.810 us; speedup vs baseline: 2.1681x; 1.0053x over previous
//
#include <hip/hip_runtime.h>
#include <math.h>

typedef float f4 __attribute__((ext_vector_type(4)));

// ---------------------------------------------------------------------------
// Kernel 1: E_k = expm(t_k * (M + M0)) via scaling-and-squaring + 12-term
// Taylor. 3x3 only (homogeneous row/col of the 4x4 never contributes since
// x_pad's last coord is 0 and A's last row is 0). One thread per t.
// ---------------------------------------------------------------------------
__global__ void expm_kernel(const float* __restrict__ t,
                            const float* __restrict__ M,
                            const float* __restrict__ M0,
                            float* __restrict__ E_out,
                            int T) {
    int k = blockIdx.x * blockDim.x + threadIdx.x;
    if (k >= T) return;

    float tk = t[k];
    float B[9];
#pragma unroll
    for (int i = 0; i < 9; ++i) B[i] = tk * (M[i] + M0[i]);

    float norm = 0.f;
#pragma unroll
    for (int i = 0; i < 3; ++i) {
        float rs = fabsf(B[i * 3]) + fabsf(B[i * 3 + 1]) + fabsf(B[i * 3 + 2]);
        norm = fmaxf(norm, rs);
    }
    int s = 0;
    while (norm > 0.25f && s < 40) { norm *= 0.5f; ++s; }
    float scale = exp2f((float)(-s));
#pragma unroll
    for (int i = 0; i < 9; ++i) B[i] *= scale;

    float P[9], E[9];
#pragma unroll
    for (int i = 0; i < 9; ++i) { P[i] = (i % 4 == 0) ? 1.f : 0.f; E[i] = P[i]; }
    for (int n = 1; n <= 12; ++n) {
        float inv = 1.0f / (float)n;
        float Q[9];
#pragma unroll
        for (int i = 0; i < 3; ++i)
#pragma unroll
            for (int j = 0; j < 3; ++j)
                Q[i * 3 + j] = (P[i * 3 + 0] * B[0 * 3 + j] +
                                P[i * 3 + 1] * B[1 * 3 + j] +
                                P[i * 3 + 2] * B[2 * 3 + j]) * inv;
#pragma unroll
        for (int i = 0; i < 9; ++i) { P[i] = Q[i]; E[i] += Q[i]; }
    }
    for (int q = 0; q < s; ++q) {
        float Q[9];
#pragma unroll
        for (int i = 0; i < 3; ++i)
#pragma unroll
            for (int j = 0; j < 3; ++j)
                Q[i * 3 + j] = E[i * 3 + 0] * E[0 * 3 + j] +
                               E[i * 3 + 1] * E[1 * 3 + j] +
                               E[i * 3 + 2] * E[2 * 3 + j];
#pragma unroll
        for (int i = 0; i < 9; ++i) E[i] = Q[i];
    }

#pragma unroll
    for (int i = 0; i < 9; ++i) E_out[k * 9 + i] = E[i];
}

// ---------------------------------------------------------------------------
// Kernel 2: OUTPUT-DENSE ownership, zero-sync streamer + NT streaming stores.
// Identical structure to round 10 (dense 1 KB/instr stores, x in registers,
// no LDS/barriers, uniform outer t = single rolling write window). ONE
// change: stores are nontemporal. Rationale: plain stores write-allocate in
// L2; the 384 MB write stream then reaches HBM in EVICTION order (per-set,
// per-XCD) not program order, destroying DRAM sequential locality (~4.9 vs
// fill's 7.0 TB/s). nt streams in program order. R5's nt amplification
// (1.94x WRITE) was caused by 48B-strided lanes emitting partial 64B
// sectors; here every sector is fully covered by a single instruction, so
// nt cannot amplify (prediction: WRITE_SIZE ~= 375,000 KB exactly).
// ---------------------------------------------------------------------------
#define NBLK 512
#define TPB 256

__global__ __launch_bounds__(TPB) void apply_kernel(const float* __restrict__ x,
                                                    const float* __restrict__ E_all,
                                                    float* __restrict__ out,
                                                    int N, int T) {
    const int tid = threadIdx.x;

    if (((N * 3) & 3) == 0) {
        const int  lane = tid & 63;
        const long wave = ((long)blockIdx.x * TPB + tid) >> 6;   // 0..2047
        const long NG4  = (long)N * 3 / 4;                       // f4 per slab
        const long base = wave * 192;
        if (base >= NG4) return;                                 // idle wave

        // per-slot setup (t-invariant): owned f4 index, phase, 2 x rows
        long J[3];
        int  p[3];
        bool act[3];
        float a0[3], a1[3], a2[3], b0[3], b1[3], b2[3];
#pragma unroll
        for (int k = 0; k < 3; ++k) {
            J[k]   = base + 64 * k + lane;
            act[k] = J[k] < NG4;
            const long e0 = 4 * J[k];
            const long n0 = e0 / 3;
            p[k] = (int)(e0 - n0 * 3);
            const long xo = act[k] ? n0 * 3 : 0;   // clamp OOB lanes
            a0[k] = x[xo + 0]; a1[k] = x[xo + 1]; a2[k] = x[xo + 2];
            b0[k] = x[xo + 3]; b1[k] = x[xo + 4]; b2[k] = x[xo + 5];
        }

        f4* const out4 = (f4*)out;

        for (int t = 0; t < T; ++t) {
            const float* Ep = E_all + t * 9;       // uniform -> scalar loads
            const float E0 = Ep[0], E1 = Ep[1], E2 = Ep[2];
            const float E3 = Ep[3], E4 = Ep[4], E5 = Ep[5];
            const float E6 = Ep[6], E7 = Ep[7], E8 = Ep[8];
            f4* const dst = out4 + (size_t)t * (size_t)NG4;

#pragma unroll
            for (int k = 0; k < 3; ++k) {
                // dots of E rows with x rows A (n0) and B (n0+1)
                const float dA0 = E0 * a0[k] + E1 * a1[k] + E2 * a2[k];
                const float dA1 = E3 * a0[k] + E4 * a1[k] + E5 * a2[k];
                const float dA2 = E6 * a0[k] + E7 * a1[k] + E8 * a2[k];
                const float dB0 = E0 * b0[k] + E1 * b1[k] + E2 * b2[k];
                const float dB1 = E3 * b0[k] + E4 * b1[k] + E5 * b2[k];
                const float dB2 = E6 * b0[k] + E7 * b1[k] + E8 * b2[k];

                // phase-rotated component mapping (masks are t-invariant)
                const bool q0 = (p[k] == 0), q1 = (p[k] == 1);
                f4 r;
                r.x = q0 ? dA0 : (q1 ? dA1 : dA2);
                r.y = q0 ? dA1 : (q1 ? dA2 : dB0);
                r.z = q0 ? dA2 : (q1 ? dB0 : dB1);
                r.w = q0 ? dB0 : (q1 ? dB1 : dB2);

                if (act[k]) __builtin_nontemporal_store(r, dst + J[k]);
            }
        }
    } else {
        // generic scalar fallback (not hit for N*3 % 4 == 0)
        const int gid      = blockIdx.x * TPB + tid;
        const int nthreads = gridDim.x * TPB;
        const size_t total = (size_t)T * (size_t)N * 3;
        for (size_t e = gid; e < total; e += (size_t)nthreads) {
            const size_t slab = (size_t)N * 3;
            const int    t    = (int)(e / slab);
            const size_t r    = e - (size_t)t * slab;
            const int    n    = (int)(r / 3);
            const int    i    = (int)(r - (size_t)n * 3);
            const float* Ep = E_all + t * 9 + i * 3;
            const float* xr = x + (size_t)n * 3;
            out[e] = Ep[0] * xr[0] + Ep[1] * xr[1] + Ep[2] * xr[2];
        }
    }
}

extern "C" void kernel_launch(void* const* d_in, const int* in_sizes, int n_in,
                              void* d_out, int out_size, void* d_ws, size_t ws_size,
                              hipStream_t stream) {
    const float* x  = (const float*)d_in[0];   // (N, 3)
    const float* t  = (const float*)d_in[1];   // (T,)
    const float* M  = (const float*)d_in[2];   // (3, 3)
    const float* M0 = (const float*)d_in[3];   // (3, 3)
    // d_in[4] = b (3,) — never contributes: homogeneous coord of x_pad is 0.

    const int N = in_sizes[0] / 3;
    const int T = in_sizes[1];

    float* E_ws = (float*)d_ws;                 // T*9 floats
    float* out  = (float*)d_out;

    expm_kernel<<<(T + 63) / 64, 64, 0, stream>>>(t, M, M0, E_ws, T);

    apply_kernel<<<NBLK, TPB, 0, stream>>>(x, E_ws, out, N, T);
}

// Round 12
// 80.740 us; speedup vs baseline: 2.2506x; 1.0380x over previous
//
#include <hip/hip_runtime.h>
#include <math.h>

typedef float f4 __attribute__((ext_vector_type(4)));

// ---------------------------------------------------------------------------
// Kernel 1: E_k = expm(t_k * (M + M0)) via scaling-and-squaring + 12-term
// Taylor. 3x3 only (homogeneous row/col of the 4x4 never contributes since
// x_pad's last coord is 0 and A's last row is 0). One thread per t.
// ---------------------------------------------------------------------------
__global__ void expm_kernel(const float* __restrict__ t,
                            const float* __restrict__ M,
                            const float* __restrict__ M0,
                            float* __restrict__ E_out,
                            int T) {
    int k = blockIdx.x * blockDim.x + threadIdx.x;
    if (k >= T) return;

    float tk = t[k];
    float B[9];
#pragma unroll
    for (int i = 0; i < 9; ++i) B[i] = tk * (M[i] + M0[i]);

    float norm = 0.f;
#pragma unroll
    for (int i = 0; i < 3; ++i) {
        float rs = fabsf(B[i * 3]) + fabsf(B[i * 3 + 1]) + fabsf(B[i * 3 + 2]);
        norm = fmaxf(norm, rs);
    }
    int s = 0;
    while (norm > 0.25f && s < 40) { norm *= 0.5f; ++s; }
    float scale = exp2f((float)(-s));
#pragma unroll
    for (int i = 0; i < 9; ++i) B[i] *= scale;

    float P[9], E[9];
#pragma unroll
    for (int i = 0; i < 9; ++i) { P[i] = (i % 4 == 0) ? 1.f : 0.f; E[i] = P[i]; }
    for (int n = 1; n <= 12; ++n) {
        float inv = 1.0f / (float)n;
        float Q[9];
#pragma unroll
        for (int i = 0; i < 3; ++i)
#pragma unroll
            for (int j = 0; j < 3; ++j)
                Q[i * 3 + j] = (P[i * 3 + 0] * B[0 * 3 + j] +
                                P[i * 3 + 1] * B[1 * 3 + j] +
                                P[i * 3 + 2] * B[2 * 3 + j]) * inv;
#pragma unroll
        for (int i = 0; i < 9; ++i) { P[i] = Q[i]; E[i] += Q[i]; }
    }
    for (int q = 0; q < s; ++q) {
        float Q[9];
#pragma unroll
        for (int i = 0; i < 3; ++i)
#pragma unroll
            for (int j = 0; j < 3; ++j)
                Q[i * 3 + j] = E[i * 3 + 0] * E[0 * 3 + j] +
                               E[i * 3 + 1] * E[1 * 3 + j] +
                               E[i * 3 + 2] * E[2 * 3 + j];
#pragma unroll
        for (int i = 0; i < 9; ++i) E[i] = Q[i];
    }

#pragma unroll
    for (int i = 0; i < 9; ++i) E_out[k * 9 + i] = E[i];
}

// ---------------------------------------------------------------------------
// Kernel 2: OUTPUT-DENSE streamer, HIGH-OCCUPANCY variant.
// Ownership shrunk to 64 f4s/wave (ONE dense 1 KB store per t per wave):
// 5860 waves = 1465 blocks, all co-resident -> ~23 waves/CU (was 8).
// Rationale: under HBM backpressure the drain rate tracks per-CU
// outstanding-store depth (MLP). fill (7 TB/s) keeps wave store queues
// saturated; our 3-store bursts every ~350 cyc at 8 waves/CU leave gaps.
// 2.9x waves + t-unroll x4 (batched uniform E-loads, 4 stores per iter)
// deepens in-flight stores. Preserved from R7-R11: uniform outer t =
// single ~6 MB rolling write window; lane-dense stores (lane l -> f4
// base+l); x in registers (read once); no LDS, no barriers; nt stores
// (dense coverage -> no amplification, R10~R11 showed nt==plain).
// ---------------------------------------------------------------------------
#define TPB 256

__global__ __launch_bounds__(TPB) void apply_kernel(const float* __restrict__ x,
                                                    const float* __restrict__ E_all,
                                                    float* __restrict__ out,
                                                    int N, int T) {
    const int tid = threadIdx.x;

    if (((N * 3) & 3) == 0) {
        const int  lane = tid & 63;
        const long wave = ((long)blockIdx.x * TPB + tid) >> 6;
        const long NG4  = (long)N * 3 / 4;         // f4 per t-slab
        const long J    = wave * 64 + lane;        // owned f4 (dense in wave)
        const bool act  = J < NG4;

        // t-invariant setup: phase + the 2 x rows feeding this f4
        const long e0 = 4 * J;
        const long n0 = e0 / 3;
        const int  p  = (int)(e0 - n0 * 3);
        const long xo = act ? n0 * 3 : 0;          // clamp OOB lanes
        const float a0 = x[xo + 0], a1 = x[xo + 1], a2 = x[xo + 2];
        const float b0 = x[xo + 3], b1 = x[xo + 4], b2 = x[xo + 5];
        const bool q0 = (p == 0), q1 = (p == 1);

        f4* dst = (f4*)out + J;

#pragma unroll 4
        for (int t = 0; t < T; ++t) {
            const float* Ep = E_all + t * 9;       // uniform -> scalar loads
            const float E0 = Ep[0], E1 = Ep[1], E2 = Ep[2];
            const float E3 = Ep[3], E4 = Ep[4], E5 = Ep[5];
            const float E6 = Ep[6], E7 = Ep[7], E8 = Ep[8];

            // dots of E rows with x rows A (n0) and B (n0+1)
            const float dA0 = E0 * a0 + E1 * a1 + E2 * a2;
            const float dA1 = E3 * a0 + E4 * a1 + E5 * a2;
            const float dA2 = E6 * a0 + E7 * a1 + E8 * a2;
            const float dB0 = E0 * b0 + E1 * b1 + E2 * b2;
            const float dB1 = E3 * b0 + E4 * b1 + E5 * b2;
            const float dB2 = E6 * b0 + E7 * b1 + E8 * b2;

            // phase-rotated component mapping (masks t-invariant)
            f4 r;
            r.x = q0 ? dA0 : (q1 ? dA1 : dA2);
            r.y = q0 ? dA1 : (q1 ? dA2 : dB0);
            r.z = q0 ? dA2 : (q1 ? dB0 : dB1);
            r.w = q0 ? dB0 : (q1 ? dB1 : dB2);

            if (act) __builtin_nontemporal_store(r, dst);
            dst += NG4;
        }
    } else {
        // generic scalar fallback (not hit for N*3 % 4 == 0)
        const int gid      = blockIdx.x * TPB + tid;
        const int nthreads = gridDim.x * TPB;
        const size_t total = (size_t)T * (size_t)N * 3;
        for (size_t e = gid; e < total; e += (size_t)nthreads) {
            const size_t slab = (size_t)N * 3;
            const int    t    = (int)(e / slab);
            const size_t r    = e - (size_t)t * slab;
            const int    n    = (int)(r / 3);
            const int    i    = (int)(r - (size_t)n * 3);
            const float* Ep = E_all + t * 9 + i * 3;
            const float* xr = x + (size_t)n * 3;
            out[e] = Ep[0] * xr[0] + Ep[1] * xr[1] + Ep[2] * xr[2];
        }
    }
}

extern "C" void kernel_launch(void* const* d_in, const int* in_sizes, int n_in,
                              void* d_out, int out_size, void* d_ws, size_t ws_size,
                              hipStream_t stream) {
    const float* x  = (const float*)d_in[0];   // (N, 3)
    const float* t  = (const float*)d_in[1];   // (T,)
    const float* M  = (const float*)d_in[2];   // (3, 3)
    const float* M0 = (const float*)d_in[3];   // (3, 3)
    // d_in[4] = b (3,) — never contributes: homogeneous coord of x_pad is 0.

    const int N = in_sizes[0] / 3;
    const int T = in_sizes[1];

    float* E_ws = (float*)d_ws;                 // T*9 floats
    float* out  = (float*)d_out;

    expm_kernel<<<(T + 63) / 64, 64, 0, stream>>>(t, M, M0, E_ws, T);

    const long NG4    = (long)N * 3 / 4;
    const long nwaves = (NG4 + 63) / 64;                 // 5860
    const int  nblk   = (int)((nwaves + 3) / 4);         // 1465, all resident
    apply_kernel<<<nblk, TPB, 0, stream>>>(x, E_ws, out, N, T);
}

// Round 13
// 79.086 us; speedup vs baseline: 2.2976x; 1.0209x over previous
//
#include <hip/hip_runtime.h>
#include <math.h>

typedef float f4 __attribute__((ext_vector_type(4)));

// ---------------------------------------------------------------------------
// FUSED kernel: per-block redundant expm (lane-parallel, ~0.5us) + R12's
// output-dense streamer. Removes the separate expm launch + graph edge
// (~4-6us serialized) and turns E loads into LDS broadcasts.
//
// Math: out[t,n,:] = expm(t_k*(M+M0)) @ x[n,:]. The homogeneous row/col of
// the 4x4 never contributes (x_pad last coord = 0, A last row = 0) -> 3x3.
//
// Streamer (levers proven over rounds 5-12):
//  - uniform outer t across grid -> ONE ~6 MB rolling write window
//    (R7: 1 window 3.9 TB/s vs ~1000 fronts 2.4 TB/s; R8 confirmed).
//  - lane-dense stores: lane l owns f4 J=wave*64+l -> every store instr is
//    64x16B = 1 KB contiguous (R9: 104 -> 85us).
//  - high occupancy: 1465 blocks, ~23 waves/CU (R12: +4%).
//  - x rows hoisted to registers once; no global reads in t-loop.
//  - nt stores (== plain when sectors fully covered; R10/R11).
// ---------------------------------------------------------------------------
#define TPB 256

__global__ __launch_bounds__(TPB) void apply_fused(const float* __restrict__ tv,
                                                   const float* __restrict__ M,
                                                   const float* __restrict__ M0,
                                                   const float* __restrict__ x,
                                                   float* __restrict__ out,
                                                   int N, int T) {
    extern __shared__ float Es[];            // T*9 floats
    const int tid = threadIdx.x;

    // ---- per-block redundant expm: lane k computes E for t=k ----
    for (int k = tid; k < T; k += TPB) {
        const float tk = tv[k];
        float B[9];
#pragma unroll
        for (int i = 0; i < 9; ++i) B[i] = tk * (M[i] + M0[i]);

        float norm = 0.f;
#pragma unroll
        for (int i = 0; i < 3; ++i) {
            float rs = fabsf(B[i * 3]) + fabsf(B[i * 3 + 1]) + fabsf(B[i * 3 + 2]);
            norm = fmaxf(norm, rs);
        }
        int s = 0;
        while (norm > 0.25f && s < 40) { norm *= 0.5f; ++s; }
        const float scale = exp2f((float)(-s));
#pragma unroll
        for (int i = 0; i < 9; ++i) B[i] *= scale;

        float P[9], E[9];
#pragma unroll
        for (int i = 0; i < 9; ++i) { P[i] = (i % 4 == 0) ? 1.f : 0.f; E[i] = P[i]; }
        for (int n = 1; n <= 12; ++n) {
            const float inv = 1.0f / (float)n;
            float Q[9];
#pragma unroll
            for (int i = 0; i < 3; ++i)
#pragma unroll
                for (int j = 0; j < 3; ++j)
                    Q[i * 3 + j] = (P[i * 3 + 0] * B[0 * 3 + j] +
                                    P[i * 3 + 1] * B[1 * 3 + j] +
                                    P[i * 3 + 2] * B[2 * 3 + j]) * inv;
#pragma unroll
            for (int i = 0; i < 9; ++i) { P[i] = Q[i]; E[i] += Q[i]; }
        }
        for (int q = 0; q < s; ++q) {
            float Q[9];
#pragma unroll
            for (int i = 0; i < 3; ++i)
#pragma unroll
                for (int j = 0; j < 3; ++j)
                    Q[i * 3 + j] = E[i * 3 + 0] * E[0 * 3 + j] +
                                   E[i * 3 + 1] * E[1 * 3 + j] +
                                   E[i * 3 + 2] * E[2 * 3 + j];
#pragma unroll
            for (int i = 0; i < 9; ++i) E[i] = Q[i];
        }
#pragma unroll
        for (int i = 0; i < 9; ++i) Es[k * 9 + i] = E[i];
    }
    __syncthreads();

    // ---- streamer ----
    if (((N * 3) & 3) == 0) {
        const int  lane = tid & 63;
        const long wave = ((long)blockIdx.x * TPB + tid) >> 6;
        const long NG4  = (long)N * 3 / 4;         // f4 per t-slab
        const long J    = wave * 64 + lane;        // owned f4 (dense in wave)
        const bool act  = J < NG4;

        // t-invariant setup: phase + the 2 x rows feeding this f4
        const long e0 = 4 * J;
        const long n0 = e0 / 3;
        const int  p  = (int)(e0 - n0 * 3);
        const long xo = act ? n0 * 3 : 0;          // clamp OOB lanes
        const float a0 = x[xo + 0], a1 = x[xo + 1], a2 = x[xo + 2];
        const float b0 = x[xo + 3], b1 = x[xo + 4], b2 = x[xo + 5];
        const bool q0 = (p == 0), q1 = (p == 1);

        f4* dst = (f4*)out + J;

#pragma unroll 4
        for (int t = 0; t < T; ++t) {
            const float* Ep = Es + t * 9;          // wave-uniform -> broadcast
            const float E0 = Ep[0], E1 = Ep[1], E2 = Ep[2];
            const float E3 = Ep[3], E4 = Ep[4], E5 = Ep[5];
            const float E6 = Ep[6], E7 = Ep[7], E8 = Ep[8];

            const float dA0 = E0 * a0 + E1 * a1 + E2 * a2;
            const float dA1 = E3 * a0 + E4 * a1 + E5 * a2;
            const float dA2 = E6 * a0 + E7 * a1 + E8 * a2;
            const float dB0 = E0 * b0 + E1 * b1 + E2 * b2;
            const float dB1 = E3 * b0 + E4 * b1 + E5 * b2;
            const float dB2 = E6 * b0 + E7 * b1 + E8 * b2;

            f4 r;
            r.x = q0 ? dA0 : (q1 ? dA1 : dA2);
            r.y = q0 ? dA1 : (q1 ? dA2 : dB0);
            r.z = q0 ? dA2 : (q1 ? dB0 : dB1);
            r.w = q0 ? dB0 : (q1 ? dB1 : dB2);

            if (act) __builtin_nontemporal_store(r, dst);
            dst += NG4;
        }
    } else {
        // generic scalar fallback (not hit for N*3 % 4 == 0)
        const int gid      = blockIdx.x * TPB + tid;
        const int nthreads = gridDim.x * TPB;
        const size_t total = (size_t)T * (size_t)N * 3;
        for (size_t e = gid; e < total; e += (size_t)nthreads) {
            const size_t slab = (size_t)N * 3;
            const int    t    = (int)(e / slab);
            const size_t r    = e - (size_t)t * slab;
            const int    n    = (int)(r / 3);
            const int    i    = (int)(r - (size_t)n * 3);
            const float* Ep = Es + t * 9 + i * 3;
            const float* xr = x + (size_t)n * 3;
            out[e] = Ep[0] * xr[0] + Ep[1] * xr[1] + Ep[2] * xr[2];
        }
    }
}

extern "C" void kernel_launch(void* const* d_in, const int* in_sizes, int n_in,
                              void* d_out, int out_size, void* d_ws, size_t ws_size,
                              hipStream_t stream) {
    const float* x  = (const float*)d_in[0];   // (N, 3)
    const float* t  = (const float*)d_in[1];   // (T,)
    const float* M  = (const float*)d_in[2];   // (3, 3)
    const float* M0 = (const float*)d_in[3];   // (3, 3)
    // d_in[4] = b (3,) — never contributes: homogeneous coord of x_pad is 0.

    const int N = in_sizes[0] / 3;
    const int T = in_sizes[1];

    float* out = (float*)d_out;

    const long NG4    = (long)N * 3 / 4;
    const long nwaves = (NG4 + 63) / 64;                 // 5860
    const int  nblk   = (int)((nwaves + 3) / 4);         // 1465, all resident
    const size_t shmem = (size_t)T * 9 * sizeof(float);  // 2304 B for T=64

    apply_fused<<<nblk, TPB, shmem, stream>>>(t, M, M0, x, out, N, T);
}